// Round 7
// baseline (271.087 us; speedup 1.0000x reference)
//
#include <hip/hip_runtime.h>
#include <cstdint>

// ---------------- problem constants ----------------
constexpr int RS  = 48;    // sigma ranks
constexpr int RC  = 144;   // feature ranks
constexpr int PP  = 27;    // feats dim
constexpr int NV  = 128;   // voxels per axis
constexpr int CHN = 128;   // MLP hidden

// ---------------- ws layout ----------------
constexpr int SIG_D  = 3 * NV * 64;    // 24576 dwords [3][128 vox][64 ranks]
constexpr int FEAT_D = 3 * NV * 160;   // 61440 dwords [3][128 vox][160 ranks]
constexpr int NPAIR  = SIG_D + FEAT_D; // 86016 dwords = 344KB
constexpr int FR_B  = 0;               // B frags  [5][2][64][8] = 5120
constexpr int FR_W1 = 5120;            // W1 frags [4][8][64][8] = 16384
constexpr int FR_W2 = 21504;           // W2 frags               = 16384
constexpr int FR_W3 = 37888;           // W3 frags [4][64][8]    = 2048
constexpr int FR_TOT = 39936;
// channel matrix X64 [Np][32] bf16 after frag region

typedef __attribute__((ext_vector_type(8))) short short8;
typedef __attribute__((ext_vector_type(4))) float f32x4;
typedef __attribute__((ext_vector_type(2))) unsigned int u32x2;
typedef __attribute__((ext_vector_type(4))) unsigned int u32x4;
typedef _Float16 h2 __attribute__((ext_vector_type(2)));

__device__ __forceinline__ short f2bf(float f) {          // RNE (prep only)
    unsigned int u = __builtin_bit_cast(unsigned int, f);
    u += 0x7fffu + ((u >> 16) & 1u);
    return (short)(u >> 16);
}
__device__ __forceinline__ unsigned int pk2bf(float a, float b) {
    unsigned short ua = __builtin_bit_cast(unsigned short, (__bf16)a);
    unsigned short ub = __builtin_bit_cast(unsigned short, (__bf16)b);
    return (unsigned int)ua | ((unsigned int)ub << 16);
}
__device__ __forceinline__ float bflo(unsigned int u) { return __builtin_bit_cast(float, u << 16); }
__device__ __forceinline__ float bfhi(unsigned int u) { return __builtin_bit_cast(float, u & 0xffff0000u); }
__device__ __forceinline__ float dot2lerp(unsigned int lodelta, h2 wv) {
#if __has_builtin(__builtin_amdgcn_fdot2)
    return __builtin_amdgcn_fdot2(__builtin_bit_cast(h2, lodelta), wv, 0.f, false);
#else
    h2 a = __builtin_bit_cast(h2, lodelta);
    return (float)a.x * (float)wv.x + (float)a.y * (float)wv.y;
#endif
}

// ---------------- prep 1: f16 (lo, delta) packed tables ----------------
__global__ void prep_tables(const float* __restrict__ sigma, const float* __restrict__ feature,
                            unsigned int* __restrict__ wt) {
    int idx = blockIdx.x * 256 + threadIdx.x;
    if (idx >= NPAIR) return;
    float lo = 0.f, hi = 0.f;
    if (idx < SIG_D) {
        int a = idx / 8192, t = idx % 8192;
        int v = t / 64, r = t % 64;
        if (r < RS) {
            lo = sigma[(a * RS + r) * NV + v];
            hi = sigma[(a * RS + r) * NV + min(v + 1, NV - 1)];
        }
    } else {
        int j = idx - SIG_D;
        int a = j / 20480, t = j % 20480;
        int v = t / 160, r = t % 160;
        if (r < RC) {
            lo = feature[(a * RC + r) * NV + v];
            hi = feature[(a * RC + r) * NV + min(v + 1, NV - 1)];
        }
    }
    _Float16 lh = (_Float16)lo;
    _Float16 dh = (_Float16)(hi - lo);
    wt[idx] = (unsigned int)__builtin_bit_cast(unsigned short, lh) |
              ((unsigned int)__builtin_bit_cast(unsigned short, dh) << 16);
}

// ---------------- prep 2: bf16 fragment-layout weights ----------------
__global__ void prep_frags(const float* __restrict__ Bm, const float* __restrict__ W1,
                           const float* __restrict__ W2, const float* __restrict__ W3,
                           short* __restrict__ fr) {
    int idx = blockIdx.x * 256 + threadIdx.x;
    if (idx >= FR_TOT) return;
    float val = 0.f;
    if (idx < FR_W1) {                          // B frags
        int j = idx - FR_B;
        int frag = j >> 9, li = (j >> 3) & 63, e = j & 7;
        int kt = frag >> 1, nt = frag & 1;
        int k = kt * 32 + (li >> 4) * 8 + e;
        int n = nt * 16 + (li & 15);
        val = (k < RC && n < PP) ? Bm[k * PP + n] : 0.f;
    } else if (idx < FR_W2) {                   // W1 frags, rows in channel*4+l order
        int j = idx - FR_W1;
        int frag = j >> 9, li = (j >> 3) & 63, e = j & 7;
        int kt = frag >> 3, nt = frag & 7;
        int kn = kt * 32 + (li >> 4) * 8 + e;
        int n = nt * 16 + (li & 15);
        if (kn < 120) {
            int ko;
            if (kn < 108) { ko = (kn & 3) * PP + (kn >> 2); }            // feats: l*27 + c
            else { int t2 = kn - 108; ko = 108 + (t2 & 3) * 3 + (t2 >> 2); } // dirs
            val = W1[ko * CHN + n];
        }
    } else if (idx < FR_W3) {                   // W2 frags
        int j = idx - FR_W2;
        int frag = j >> 9, li = (j >> 3) & 63, e = j & 7;
        int kt = frag >> 3, nt = frag & 7;
        int k = kt * 32 + (li >> 4) * 8 + e;
        int n = nt * 16 + (li & 15);
        val = W2[k * CHN + n];
    } else {                                    // W3 frags
        int j = idx - FR_W3;
        int frag = j >> 9, li = (j >> 3) & 63, e = j & 7;
        int kt = frag;
        int k = kt * 32 + (li >> 4) * 8 + e;
        int n = li & 15;
        val = (n < 3) ? W3[k * 3 + n] : 0.f;
    }
    fr[idx] = f2bf(val);
}

// lerp 8 ranks already in registers: 1 fdot2/rank
__device__ __forceinline__ void lerpregs(u32x4 A, u32x4 Bv, h2 wv, float* pr, bool first) {
#pragma unroll
    for (int d = 0; d < 4; ++d) {
        float s0 = dot2lerp(A[d], wv);
        float s1 = dot2lerp(Bv[d], wv);
        if (first) { pr[d] = s0; pr[4 + d] = s1; }
        else       { pr[d] *= s0; pr[4 + d] *= s1; }
    }
}
// (kept for fused fallback)
__device__ __forceinline__ void lerpf8(const unsigned int* rl, h2 wv, float* pr, bool first) {
    u32x4 A  = *(const u32x4*)rl;
    u32x4 Bv = *(const u32x4*)(rl + 4);
    lerpregs(A, Bv, wv, pr, first);
}

// ================= PHASE A: gather/lerp -> sigma + 32-channel vector =================
// 12-deep explicit load pipeline (double-buffered bL/bH register arrays).
// __launch_bounds__(256,5): VGPR <= 102 (room for 12 in-flight dwordx4), 20 waves/CU.
__global__ __launch_bounds__(256, 5)
void phaseA(const float* __restrict__ xyz, const float* __restrict__ dird,
            const float* __restrict__ voxel,
            const unsigned int* __restrict__ wt, const short* __restrict__ fr,
            float* __restrict__ out, unsigned short* __restrict__ X64, int Np) {
    __shared__ float voxs[3 * NV];
    const int tid = threadIdx.x;
    const int wid = tid >> 6;
    const int lane = tid & 63;
    const int quad = lane >> 4, lane16 = lane & 15;
    const int wavebase = blockIdx.x * 64 + wid * 16;
    const int p = wavebase + lane16;

    for (int i = tid; i < 3 * NV; i += 256) voxs[i] = voxel[i];
    __syncthreads();

    const unsigned int* SIGU  = wt;
    const unsigned int* FEATU = wt + SIG_D;
    const short* BFr = fr + FR_B;

    int ipb[3]; h2 wv[3];
#pragma unroll
    for (int a = 0; a < 3; ++a) {
        float x = xyz[p * 3 + a];
        int ind = (int)ceilf(x * 127.f);
        ind = min(max(ind, 0), 128);
        while (ind > 0 && voxs[a * NV + ind - 1] >= x) --ind;   // searchsorted-left fixup
        while (ind < 128 && voxs[a * NV + ind] < x) ++ind;
        int il = min(max(ind - 1, 0), 127);
        int ir = min(ind, 127);
        float vl = voxs[a * NV + il], vr = voxs[a * NV + ir];
        float w = (x - vl) / (vr - vl + 1e-6f);
        w = (il == 127) ? 1.f : w;
        ipb[a] = min(il, 126);
        wv[a] = h2{(_Float16)1.0f, (_Float16)w};
    }

    const unsigned int* sbase[3];
    const unsigned int* fbase[3];
#pragma unroll
    for (int a = 0; a < 3; ++a) {
        sbase[a] = SIGU  + (a * NV + ipb[a]) * 64  + quad * 8;
        fbase[a] = FEATU + (a * NV + ipb[a]) * 160 + quad * 8;
    }

    // ---- pipeline: issue sigma kt0 + kt1 (12 loads in flight) ----
    u32x4 bL[2][3], bH[2][3];
#pragma unroll
    for (int a = 0; a < 3; ++a) {
        bL[0][a] = *(const u32x4*)(sbase[a]);
        bH[0][a] = *(const u32x4*)(sbase[a] + 4);
    }
#pragma unroll
    for (int a = 0; a < 3; ++a) {
        bL[1][a] = *(const u32x4*)(sbase[a] + 32);
        bH[1][a] = *(const u32x4*)(sbase[a] + 36);
    }

    float sig = 0.f;
    {   // compute sigma kt0 (waits only for first 6 loads)
        float pr[8];
#pragma unroll
        for (int a = 0; a < 3; ++a) lerpregs(bL[0][a], bH[0][a], wv[a], pr, a == 0);
#pragma unroll
        for (int j = 0; j < 8; ++j) sig += pr[j];
    }
    // prefetch feats kt0 into slot 0
#pragma unroll
    for (int a = 0; a < 3; ++a) {
        bL[0][a] = *(const u32x4*)(fbase[a]);
        bH[0][a] = *(const u32x4*)(fbase[a] + 4);
    }
    {   // compute sigma kt1
        float pr[8];
#pragma unroll
        for (int a = 0; a < 3; ++a) lerpregs(bL[1][a], bH[1][a], wv[a], pr, a == 0);
#pragma unroll
        for (int j = 0; j < 8; ++j) sig += pr[j];
    }
    sig += __shfl_xor(sig, 16);
    sig += __shfl_xor(sig, 32);
    if (lane < 16) out[p] = log1pf(expf(sig - 5.f));   // softplus(sig + bias)

    // ---- feats loop: prefetch kt+1 while computing kt ----
    f32x4 acc0 = {0.f, 0.f, 0.f, 0.f}, acc1 = {0.f, 0.f, 0.f, 0.f};
#pragma unroll
    for (int kt = 0; kt < 5; ++kt) {
        const int cur = kt & 1, nxt = cur ^ 1;
        if (kt < 4) {
#pragma unroll
            for (int a = 0; a < 3; ++a) {
                bL[nxt][a] = *(const u32x4*)(fbase[a] + (kt + 1) * 32);
                bH[nxt][a] = *(const u32x4*)(fbase[a] + (kt + 1) * 32 + 4);
            }
        }
        float pr[8];
#pragma unroll
        for (int a = 0; a < 3; ++a) lerpregs(bL[cur][a], bH[cur][a], wv[a], pr, a == 0);
        u32x4 uu;
#pragma unroll
        for (int d = 0; d < 4; ++d) uu[d] = pk2bf(pr[2 * d], pr[2 * d + 1]);
        short8 af = __builtin_bit_cast(short8, uu);
        short8 bf0 = *(const short8*)(BFr + ((kt * 2 + 0) * 64 + lane) * 8);
        short8 bf1 = *(const short8*)(BFr + ((kt * 2 + 1) * 64 + lane) * 8);
        acc0 = __builtin_amdgcn_mfma_f32_16x16x32_bf16(af, bf0, acc0, 0, 0, 0);
        acc1 = __builtin_amdgcn_mfma_f32_16x16x32_bf16(af, bf1, acc1, 0, 0, 0);
    }

    // ---- store channel vector ----
#pragma unroll
    for (int nt = 0; nt < 2; ++nt) {
        int c = nt * 16 + lane16;
        f32x4 A = nt ? acc1 : acc0;
        if (c < PP) {
#pragma unroll
            for (int j = 0; j < 4; ++j) {
                int prow = wavebase + quad * 4 + j;
                X64[prow * 32 + c] = (unsigned short)__builtin_bit_cast(unsigned short, (__bf16)A[j]);
            }
        }
    }
    if (quad < 3) {
        float d = dird[p * 3 + quad];
        X64[p * 32 + 27 + quad] = (unsigned short)__builtin_bit_cast(unsigned short, (__bf16)d);
    } else {
        *(unsigned int*)(X64 + p * 32 + 30) = 0u;
    }
}

// ================= PHASE B: encode + 3-layer MLP =================
// Wave-private transpose tile -> NO barriers needed (in-wave lgkmcnt ordering).
__global__ __launch_bounds__(256, 8)
void phaseB(const unsigned short* __restrict__ X64, const short* __restrict__ fr,
            const float* __restrict__ b1, const float* __restrict__ b2,
            const float* __restrict__ b3, float* __restrict__ out, int Np) {
    __shared__ char T[4 * 16 * 256];
    const int tid = threadIdx.x;
    const int wid = tid >> 6;
    const int lane = tid & 63;
    const int quad = lane >> 4, lane16 = lane & 15;
    const int rowbase = blockIdx.x * 64 + wid * 16;
    char* Tw = T + wid * 16 * 256;

    const short* W1F = fr + FR_W1;
    const short* W2F = fr + FR_W2;
    const short* W3F = fr + FR_W3;

    // ---- load 2 channels per kt, encode in-register -> layer-1 A-frags ----
    short8 af[4];
#pragma unroll
    for (int kt = 0; kt < 4; ++kt) {
        unsigned int d = *(const unsigned int*)(X64 + (rowbase + lane16) * 32 + kt * 8 + quad * 2);
        float f0 = bflo(d), f1 = bfhi(d);
        float s1 = __sinf(f0), c1 = __cosf(f0);
        float s2 = 2.f * s1 * c1, c2 = fmaf(-2.f * s1, s1, 1.f);
        float s1b = __sinf(f1), c1b = __cosf(f1);
        float s2b = 2.f * s1b * c1b, c2b = fmaf(-2.f * s1b, s1b, 1.f);
        u32x4 uu = {pk2bf(s1, c1), pk2bf(s2, c2), pk2bf(s1b, c1b), pk2bf(s2b, c2b)};
        af[kt] = __builtin_bit_cast(short8, uu);
    }

    // ---- layers 1 & 2 ----
#pragma unroll 1
    for (int layer = 0; layer < 2; ++layer) {
        const short* WF = layer ? W2F : W1F;
        const float* bb = layer ? b2 : b1;
#pragma unroll 2
        for (int nt = 0; nt < 8; ++nt) {
            short8 wfv[4];
#pragma unroll
            for (int kt = 0; kt < 4; ++kt)
                wfv[kt] = *(const short8*)(WF + ((kt * 8 + nt) * 64 + lane) * 8);
            f32x4 acc = {0.f, 0.f, 0.f, 0.f};
#pragma unroll
            for (int kt = 0; kt < 4; ++kt)
                acc = __builtin_amdgcn_mfma_f32_16x16x32_bf16(af[kt], wfv[kt], acc, 0, 0, 0);

            float bvv = bb[nt * 16 + lane16];
#pragma unroll
            for (int j = 0; j < 4; ++j) {
                float v = acc[j] + bvv;
                v = fmaxf(v, 0.01f * v);                // leaky relu
                int row = quad * 4 + j;
                int byte = (nt * 16 + lane16) * 2;
                int chunk = byte >> 4, off = byte & 15;
                *(short*)(Tw + row * 256 + ((chunk ^ (row & 7)) << 4) + off) =
                    (short)__builtin_bit_cast(unsigned short, (__bf16)v);
            }
        }
        // wave-private tile: in-wave LDS ordering suffices, no __syncthreads
#pragma unroll
        for (int kt = 0; kt < 4; ++kt) {
            int row = lane16;
            int chunk = kt * 4 + quad;
            af[kt] = *(const short8*)(Tw + row * 256 + ((chunk ^ (row & 7)) << 4));
        }
    }

    // ---- layer 3: 128 -> 3 (+sigmoid) ----
    {
        short8 wf3[4];
#pragma unroll
        for (int kt = 0; kt < 4; ++kt)
            wf3[kt] = *(const short8*)(W3F + (kt * 64 + lane) * 8);
        f32x4 acc3 = {0.f, 0.f, 0.f, 0.f};
#pragma unroll
        for (int kt = 0; kt < 4; ++kt)
            acc3 = __builtin_amdgcn_mfma_f32_16x16x32_bf16(af[kt], wf3[kt], acc3, 0, 0, 0);

        if (lane16 < 3) {
            float bvv = b3[lane16];
#pragma unroll
            for (int j = 0; j < 4; ++j) {
                float v = acc3[j] + bvv;
                float r = 1.f / (1.f + expf(-v));       // sigmoid
                int row = quad * 4 + j;
                out[Np + (rowbase + row) * 3 + lane16] = r;
            }
        }
    }
}

// ================= fused fallback (R5 kernel) if ws too small =================
__global__ __launch_bounds__(128, 4)
void tensorf_fused(const float* __restrict__ xyz, const float* __restrict__ dird,
                   const float* __restrict__ voxel,
                   const float* __restrict__ b1, const float* __restrict__ b2,
                   const float* __restrict__ b3,
                   const unsigned int* __restrict__ wt, const short* __restrict__ fr,
                   float* __restrict__ out, int Np) {
    __shared__ float voxs[3 * NV];
    __shared__ char  X[2 * 32 * 256];

    const int tid = threadIdx.x;
    const int wid = tid >> 6;
    const int lane = tid & 63;
    const int quad = lane >> 4, lane16 = lane & 15;
    const int wavebase = blockIdx.x * 64 + wid * 32;
    char* Xw = X + wid * 32 * 256;

    for (int i = tid; i < 3 * NV; i += 128) voxs[i] = voxel[i];
    __syncthreads();

    const unsigned int* SIGU  = wt;
    const unsigned int* FEATU = wt + SIG_D;
    const short* BFr = fr + FR_B;

#pragma unroll 1
    for (int q = 0; q < 2; ++q) {
        const int rowbase = q * 16;
        const int p = wavebase + rowbase + lane16;
        int ipb[3]; h2 wv[3];
#pragma unroll
        for (int a = 0; a < 3; ++a) {
            float x = xyz[p * 3 + a];
            int ind = (int)ceilf(x * 127.f);
            ind = min(max(ind, 0), 128);
            while (ind > 0 && voxs[a * NV + ind - 1] >= x) --ind;
            while (ind < 128 && voxs[a * NV + ind] < x) ++ind;
            int il = min(max(ind - 1, 0), 127);
            int ir = min(ind, 127);
            float vl = voxs[a * NV + il], vr = voxs[a * NV + ir];
            float w = (x - vl) / (vr - vl + 1e-6f);
            w = (il == 127) ? 1.f : w;
            ipb[a] = min(il, 126);
            wv[a] = h2{(_Float16)1.0f, (_Float16)w};
        }
        float sig = 0.f;
#pragma unroll
        for (int kt = 0; kt < 2; ++kt) {
            float pr[8];
#pragma unroll
            for (int a = 0; a < 3; ++a)
                lerpf8(SIGU + (a * NV + ipb[a]) * 64 + kt * 32 + quad * 8, wv[a], pr, a == 0);
#pragma unroll
            for (int j = 0; j < 8; ++j) sig += pr[j];
        }
        sig += __shfl_xor(sig, 16);
        sig += __shfl_xor(sig, 32);
        if (lane < 16) out[p] = log1pf(expf(sig - 5.f));

        f32x4 acc0 = {0.f, 0.f, 0.f, 0.f}, acc1 = {0.f, 0.f, 0.f, 0.f};
#pragma unroll
        for (int kt = 0; kt < 5; ++kt) {
            float pr[8];
#pragma unroll
            for (int a = 0; a < 3; ++a)
                lerpf8(FEATU + (a * NV + ipb[a]) * 160 + kt * 32 + quad * 8, wv[a], pr, a == 0);
            u32x4 uu;
#pragma unroll
            for (int d = 0; d < 4; ++d) uu[d] = pk2bf(pr[2 * d], pr[2 * d + 1]);
            short8 af = __builtin_bit_cast(short8, uu);
            short8 bf0 = *(const short8*)(BFr + ((kt * 2 + 0) * 64 + lane) * 8);
            short8 bf1 = *(const short8*)(BFr + ((kt * 2 + 1) * 64 + lane) * 8);
            acc0 = __builtin_amdgcn_mfma_f32_16x16x32_bf16(af, bf0, acc0, 0, 0, 0);
            acc1 = __builtin_amdgcn_mfma_f32_16x16x32_bf16(af, bf1, acc1, 0, 0, 0);
        }
#pragma unroll
        for (int nt = 0; nt < 2; ++nt) {
            int c = nt * 16 + lane16;
            f32x4 A = nt ? acc1 : acc0;
            if (c < PP) {
#pragma unroll
                for (int j = 0; j < 4; ++j) {
                    int row = rowbase + quad * 4 + j;
                    float f = A[j];
                    float s1 = __sinf(f), c1 = __cosf(f);
                    float s2 = 2.f * s1 * c1;
                    float c2 = fmaf(-2.f * s1, s1, 1.f);
                    unsigned int w0 = pk2bf(s1, c1);
                    unsigned int w1 = pk2bf(s2, c2);
                    int byte = c * 8;
                    int chunk = byte >> 4, off = byte & 15;
                    *(u32x2*)(Xw + row * 256 + ((chunk ^ (row & 7)) << 4) + off) = u32x2{w0, w1};
                }
            }
        }
        {
            int row = rowbase + lane16;
            if (quad < 3) {
                float d = dird[p * 3 + quad];
                float s1 = __sinf(d), c1 = __cosf(d);
                float s2 = 2.f * s1 * c1;
                float c2 = fmaf(-2.f * s1, s1, 1.f);
                unsigned int w0 = pk2bf(s1, c1);
                unsigned int w1 = pk2bf(s2, c2);
                int byte = 216 + 8 * quad;
                int chunk = byte >> 4, off = byte & 15;
                *(u32x2*)(Xw + row * 256 + ((chunk ^ (row & 7)) << 4) + off) = u32x2{w0, w1};
            } else {
                int addr = row * 256 + ((15 ^ (row & 7)) << 4);
                *(u32x4*)(Xw + addr) = u32x4{0u, 0u, 0u, 0u};
            }
        }
    }
    __syncthreads();

    const short* W1F = fr + FR_W1;
    const short* W2F = fr + FR_W2;
    const short* W3F = fr + FR_W3;

#pragma unroll 1
    for (int layer = 0; layer < 2; ++layer) {
        const short* WF = layer ? W2F : W1F;
        const float* bb = layer ? b2 : b1;
        short8 af[2][4];
#pragma unroll
        for (int m = 0; m < 2; ++m)
#pragma unroll
            for (int kt = 0; kt < 4; ++kt) {
                int row = m * 16 + lane16;
                int chunk = kt * 4 + quad;
                af[m][kt] = *(const short8*)(Xw + row * 256 + ((chunk ^ (row & 7)) << 4));
            }
#pragma unroll 1
        for (int nt = 0; nt < 8; ++nt) {
            short8 wfv[4];
#pragma unroll
            for (int kt = 0; kt < 4; ++kt)
                wfv[kt] = *(const short8*)(WF + ((kt * 8 + nt) * 64 + lane) * 8);
            f32x4 acc[2];
#pragma unroll
            for (int m = 0; m < 2; ++m) acc[m] = {0.f, 0.f, 0.f, 0.f};
#pragma unroll
            for (int m = 0; m < 2; ++m)
#pragma unroll
                for (int kt = 0; kt < 4; ++kt)
                    acc[m] = __builtin_amdgcn_mfma_f32_16x16x32_bf16(af[m][kt], wfv[kt], acc[m], 0, 0, 0);
            float bvv = bb[nt * 16 + lane16];
#pragma unroll
            for (int m = 0; m < 2; ++m) {
#pragma unroll
                for (int j = 0; j < 4; ++j) {
                    float v = acc[m][j] + bvv;
                    v = fmaxf(v, 0.01f * v);
                    int row = m * 16 + quad * 4 + j;
                    int byte = (nt * 16 + lane16) * 2;
                    int chunk = byte >> 4, off = byte & 15;
                    *(short*)(Xw + row * 256 + ((chunk ^ (row & 7)) << 4) + off) =
                        (short)__builtin_bit_cast(unsigned short, (__bf16)v);
                }
            }
        }
        __syncthreads();
    }
    {
        short8 af[2][4];
#pragma unroll
        for (int m = 0; m < 2; ++m)
#pragma unroll
            for (int kt = 0; kt < 4; ++kt) {
                int row = m * 16 + lane16;
                int chunk = kt * 4 + quad;
                af[m][kt] = *(const short8*)(Xw + row * 256 + ((chunk ^ (row & 7)) << 4));
            }
        short8 wf3[4];
#pragma unroll
        for (int kt = 0; kt < 4; ++kt)
            wf3[kt] = *(const short8*)(W3F + (kt * 64 + lane) * 8);
        f32x4 acc3[2];
#pragma unroll
        for (int m = 0; m < 2; ++m) acc3[m] = {0.f, 0.f, 0.f, 0.f};
#pragma unroll
        for (int m = 0; m < 2; ++m)
#pragma unroll
            for (int kt = 0; kt < 4; ++kt)
                acc3[m] = __builtin_amdgcn_mfma_f32_16x16x32_bf16(af[m][kt], wf3[kt], acc3[m], 0, 0, 0);
        if (lane16 < 3) {
            float bvv = b3[lane16];
#pragma unroll
            for (int m = 0; m < 2; ++m) {
#pragma unroll
                for (int j = 0; j < 4; ++j) {
                    float v = acc3[m][j] + bvv;
                    float r = 1.f / (1.f + expf(-v));
                    int row = m * 16 + quad * 4 + j;
                    out[Np + (wavebase + row) * 3 + lane16] = r;
                }
            }
        }
    }
}

// ---------------- launch ----------------
extern "C" void kernel_launch(void* const* d_in, const int* in_sizes, int n_in,
                              void* d_out, int out_size, void* d_ws, size_t ws_size,
                              hipStream_t stream) {
    (void)n_in; (void)out_size;
    const float* xyz      = (const float*)d_in[0];
    const float* dird     = (const float*)d_in[1];
    const float* voxel    = (const float*)d_in[2];
    const float* sigma    = (const float*)d_in[3];
    const float* feature  = (const float*)d_in[4];
    const float* Bm       = (const float*)d_in[5];
    const float* W1       = (const float*)d_in[6];
    const float* b1       = (const float*)d_in[7];
    const float* W2       = (const float*)d_in[8];
    const float* b2       = (const float*)d_in[9];
    const float* W3       = (const float*)d_in[10];
    const float* b3       = (const float*)d_in[11];
    float* out = (float*)d_out;
    unsigned int* wt = (unsigned int*)d_ws;
    short* frg = (short*)d_ws + 2 * (size_t)NPAIR;

    const int Np = in_sizes[0] / 3;   // 524288
    const size_t base = (size_t)NPAIR * 4 + (size_t)FR_TOT * 2;   // 423936 B
    const size_t need = base + (size_t)Np * 64;                    // + 33.5 MB

    prep_tables<<<(NPAIR + 255) / 256, 256, 0, stream>>>(sigma, feature, wt);
    prep_frags<<<(FR_TOT + 255) / 256, 256, 0, stream>>>(Bm, W1, W2, W3, frg);

    if (ws_size >= need) {
        unsigned short* X64 = (unsigned short*)((char*)d_ws + base);
        phaseA<<<Np / 64, 256, 0, stream>>>(xyz, dird, voxel, wt, frg, out, X64, Np);
        phaseB<<<Np / 64, 256, 0, stream>>>(X64, frg, b1, b2, b3, out, Np);
    } else {
        tensorf_fused<<<Np / 64, 128, 0, stream>>>(xyz, dird, voxel, b1, b2, b3, wt, frg, out, Np);
    }
}

// Round 8
// 237.917 us; speedup vs baseline: 1.1394x; 1.1394x over previous
//
#include <hip/hip_runtime.h>
#include <cstdint>

// ---------------- problem constants ----------------
constexpr int RS  = 48;
constexpr int RC  = 144;
constexpr int PP  = 27;
constexpr int NV  = 128;
constexpr int CHN = 128;

// ---------------- ws layout ----------------
constexpr int SIG_D  = 3 * NV * 64;    // 24576 dwords
constexpr int FEAT_D = 3 * NV * 160;   // 61440 dwords
constexpr int NPAIR  = SIG_D + FEAT_D; // 86016 dwords = 344KB
constexpr int FR_B  = 0;               // B frags  [5][2][64][8] = 5120 shorts
constexpr int FR_W1 = 5120;            // W1 frags [4][8][64][8] = 16384
constexpr int FR_W2 = 21504;
constexpr int FR_W3 = 37888;           // [4][64][8] = 2048
constexpr int FR_TOT = 39936;

typedef __attribute__((ext_vector_type(8))) short short8;
typedef __attribute__((ext_vector_type(4))) float f32x4;
typedef __attribute__((ext_vector_type(2))) unsigned int u32x2;
typedef __attribute__((ext_vector_type(4))) unsigned int u32x4;
typedef _Float16 h2 __attribute__((ext_vector_type(2)));

__device__ __forceinline__ short f2bf(float f) {
    unsigned int u = __builtin_bit_cast(unsigned int, f);
    u += 0x7fffu + ((u >> 16) & 1u);
    return (short)(u >> 16);
}
__device__ __forceinline__ unsigned int pk2bf(float a, float b) {
    unsigned short ua = __builtin_bit_cast(unsigned short, (__bf16)a);
    unsigned short ub = __builtin_bit_cast(unsigned short, (__bf16)b);
    return (unsigned int)ua | ((unsigned int)ub << 16);
}
__device__ __forceinline__ float bflo(unsigned int u) { return __builtin_bit_cast(float, u << 16); }
__device__ __forceinline__ float bfhi(unsigned int u) { return __builtin_bit_cast(float, u & 0xffff0000u); }
__device__ __forceinline__ float dot2lerp(unsigned int lodelta, h2 wv) {
#if __has_builtin(__builtin_amdgcn_fdot2)
    return __builtin_amdgcn_fdot2(__builtin_bit_cast(h2, lodelta), wv, 0.f, false);
#else
    h2 a = __builtin_bit_cast(h2, lodelta);
    return (float)a.x * (float)wv.x + (float)a.y * (float)wv.y;
#endif
}

// inline-asm gather with literal offset; early-clobber dest; volatile keeps issue order
#define GLO(dst, base, OFF) \
    asm volatile("global_load_dwordx4 %0, %1, off offset:" OFF : "=&v"(dst) : "v"(base))
// counted wait + scheduling fence (rule #18)
#define WAITV(N) do { asm volatile("s_waitcnt vmcnt(" #N ")" ::: "memory"); \
                      __builtin_amdgcn_sched_barrier(0); } while (0)
#define ISSUE_F(buf, O1, O2) do { \
    GLO(buf[0], fb0, O1); GLO(buf[1], fb0, O2); \
    GLO(buf[2], fb1, O1); GLO(buf[3], fb1, O2); \
    GLO(buf[4], fb2, O1); GLO(buf[5], fb2, O2); } while (0)

// ---------------- prep 1: f16 (lo, delta) packed tables ----------------
__global__ void prep_tables(const float* __restrict__ sigma, const float* __restrict__ feature,
                            unsigned int* __restrict__ wt) {
    int idx = blockIdx.x * 256 + threadIdx.x;
    if (idx >= NPAIR) return;
    float lo = 0.f, hi = 0.f;
    if (idx < SIG_D) {
        int a = idx / 8192, t = idx % 8192;
        int v = t / 64, r = t % 64;
        if (r < RS) {
            lo = sigma[(a * RS + r) * NV + v];
            hi = sigma[(a * RS + r) * NV + min(v + 1, NV - 1)];
        }
    } else {
        int j = idx - SIG_D;
        int a = j / 20480, t = j % 20480;
        int v = t / 160, r = t % 160;
        if (r < RC) {
            lo = feature[(a * RC + r) * NV + v];
            hi = feature[(a * RC + r) * NV + min(v + 1, NV - 1)];
        }
    }
    _Float16 lh = (_Float16)lo;
    _Float16 dh = (_Float16)(hi - lo);
    wt[idx] = (unsigned int)__builtin_bit_cast(unsigned short, lh) |
              ((unsigned int)__builtin_bit_cast(unsigned short, dh) << 16);
}

// ---------------- prep 2: bf16 fragment-layout weights ----------------
__global__ void prep_frags(const float* __restrict__ Bm, const float* __restrict__ W1,
                           const float* __restrict__ W2, const float* __restrict__ W3,
                           short* __restrict__ fr) {
    int idx = blockIdx.x * 256 + threadIdx.x;
    if (idx >= FR_TOT) return;
    float val = 0.f;
    if (idx < FR_W1) {                          // B frags
        int j = idx - FR_B;
        int frag = j >> 9, li = (j >> 3) & 63, e = j & 7;
        int kt = frag >> 1, nt = frag & 1;
        int k = kt * 32 + (li >> 4) * 8 + e;
        int n = nt * 16 + (li & 15);
        val = (k < RC && n < PP) ? Bm[k * PP + n] : 0.f;
    } else if (idx < FR_W2) {                   // W1 frags, permuted rows
        int j = idx - FR_W1;
        int frag = j >> 9, li = (j >> 3) & 63, e = j & 7;
        int kt = frag >> 3, nt = frag & 7;
        int kn = kt * 32 + (li >> 4) * 8 + e;
        int n = nt * 16 + (li & 15);
        if (kn < 120) {
            int ko;
            if (kn < 108) { ko = (kn & 3) * PP + (kn >> 2); }
            else { int t2 = kn - 108; ko = 108 + (t2 & 3) * 3 + (t2 >> 2); }
            val = W1[ko * CHN + n];
        }
    } else if (idx < FR_W3) {                   // W2 frags
        int j = idx - FR_W2;
        int frag = j >> 9, li = (j >> 3) & 63, e = j & 7;
        int kt = frag >> 3, nt = frag & 7;
        int k = kt * 32 + (li >> 4) * 8 + e;
        int n = nt * 16 + (li & 15);
        val = W2[k * CHN + n];
    } else {                                    // W3 frags
        int j = idx - FR_W3;
        int frag = j >> 9, li = (j >> 3) & 63, e = j & 7;
        int kt = frag;
        int k = kt * 32 + (li >> 4) * 8 + e;
        int n = li & 15;
        val = (n < 3) ? W3[k * 3 + n] : 0.f;
    }
    fr[idx] = f2bf(val);
}

__device__ __forceinline__ void lerpregs(u32x4 A, u32x4 Bv, h2 wv, float* pr, bool first) {
#pragma unroll
    for (int d = 0; d < 4; ++d) {
        float s0 = dot2lerp(A[d], wv);
        float s1 = dot2lerp(Bv[d], wv);
        if (first) { pr[d] = s0; pr[4 + d] = s1; }
        else       { pr[d] *= s0; pr[4 + d] *= s1; }
    }
}
__device__ __forceinline__ void lerpf8(const unsigned int* rl, h2 wv, float* pr, bool first) {
    u32x4 A  = *(const u32x4*)rl;
    u32x4 Bv = *(const u32x4*)(rl + 4);
    lerpregs(A, Bv, wv, pr, first);
}

// ================= PHASE A: asm-pipelined gather/lerp -> sigma + channel vector =======
// All table gathers via inline-asm global_load_dwordx4 + counted vmcnt (compiler can't
// collapse the pipeline). B-frags staged in LDS (lgkmcnt — doesn't pollute vmcnt ledger).
__global__ __launch_bounds__(256, 4)
void phaseA(const float* __restrict__ xyz, const float* __restrict__ dird,
            const float* __restrict__ voxel,
            const unsigned int* __restrict__ wt, const short* __restrict__ fr,
            float* __restrict__ out, unsigned short* __restrict__ X64, int Np) {
    __shared__ float voxs[3 * NV];
    __shared__ short bfrs[5120];           // B frags, 10KB

    const int tid = threadIdx.x;
    const int wid = tid >> 6;
    const int lane = tid & 63;
    const int quad = lane >> 4, lane16 = lane & 15;
    const int wavebase = blockIdx.x * 64 + wid * 16;
    const int p = wavebase + lane16;

    for (int i = tid; i < 3 * NV; i += 256) voxs[i] = voxel[i];
    for (int i = tid; i < 640; i += 256)
        ((short8*)bfrs)[i] = ((const short8*)(fr + FR_B))[i];
    __syncthreads();

    const unsigned int* SIGU  = wt;
    const unsigned int* FEATU = wt + SIG_D;

    int ipb[3]; h2 wv[3];
#pragma unroll
    for (int a = 0; a < 3; ++a) {
        float x = xyz[p * 3 + a];
        int ind = (int)ceilf(x * 127.f);
        ind = min(max(ind, 0), 128);
        while (ind > 0 && voxs[a * NV + ind - 1] >= x) --ind;
        while (ind < 128 && voxs[a * NV + ind] < x) ++ind;
        int il = min(max(ind - 1, 0), 127);
        int ir = min(ind, 127);
        float vl = voxs[a * NV + il], vr = voxs[a * NV + ir];
        float w = (x - vl) / (vr - vl + 1e-6f);
        w = (il == 127) ? 1.f : w;
        ipb[a] = min(il, 126);
        wv[a] = h2{(_Float16)1.0f, (_Float16)w};
    }

    const unsigned int* sb0 = SIGU + (0 * NV + ipb[0]) * 64 + quad * 8;
    const unsigned int* sb1 = SIGU + (1 * NV + ipb[1]) * 64 + quad * 8;
    const unsigned int* sb2 = SIGU + (2 * NV + ipb[2]) * 64 + quad * 8;
    const unsigned int* fb0 = FEATU + (0 * NV + ipb[0]) * 160 + quad * 8;
    const unsigned int* fb1 = FEATU + (1 * NV + ipb[1]) * 160 + quad * 8;
    const unsigned int* fb2 = FEATU + (2 * NV + ipb[2]) * 160 + quad * 8;

    // ---- issue sigma kt0(6) + kt1(6): 12 in flight ----
    u32x4 S[12];
    GLO(S[0], sb0, "0");   GLO(S[1], sb0, "16");
    GLO(S[2], sb1, "0");   GLO(S[3], sb1, "16");
    GLO(S[4], sb2, "0");   GLO(S[5], sb2, "16");
    GLO(S[6], sb0, "128"); GLO(S[7], sb0, "144");
    GLO(S[8], sb1, "128"); GLO(S[9], sb1, "144");
    GLO(S[10], sb2, "128"); GLO(S[11], sb2, "144");

    float sig = 0.f;
    WAITV(6);                               // sigma kt0 arrived
    {
        float pr[8];
        lerpregs(S[0], S[1], wv[0], pr, true);
        lerpregs(S[2], S[3], wv[1], pr, false);
        lerpregs(S[4], S[5], wv[2], pr, false);
#pragma unroll
        for (int j = 0; j < 8; ++j) sig += pr[j];
    }
    u32x4 Fa[6], Fb[6];
    ISSUE_F(Fa, "0", "16");                 // feats kt0 -> outstanding 12
    WAITV(6);                               // sigma kt1 arrived
    {
        float pr[8];
        lerpregs(S[6], S[7], wv[0], pr, true);
        lerpregs(S[8], S[9], wv[1], pr, false);
        lerpregs(S[10], S[11], wv[2], pr, false);
#pragma unroll
        for (int j = 0; j < 8; ++j) sig += pr[j];
    }
    sig += __shfl_xor(sig, 16);
    sig += __shfl_xor(sig, 32);

    f32x4 acc0 = {0.f, 0.f, 0.f, 0.f}, acc1 = {0.f, 0.f, 0.f, 0.f};
    auto compute_kt = [&](const u32x4* Fx, int kt) {
        float pr[8];
        lerpregs(Fx[0], Fx[1], wv[0], pr, true);
        lerpregs(Fx[2], Fx[3], wv[1], pr, false);
        lerpregs(Fx[4], Fx[5], wv[2], pr, false);
        u32x4 uu;
#pragma unroll
        for (int d = 0; d < 4; ++d) uu[d] = pk2bf(pr[2 * d], pr[2 * d + 1]);
        short8 af = __builtin_bit_cast(short8, uu);
        short8 bf0 = *(const short8*)(bfrs + ((kt * 2 + 0) * 64 + lane) * 8);
        short8 bf1 = *(const short8*)(bfrs + ((kt * 2 + 1) * 64 + lane) * 8);
        acc0 = __builtin_amdgcn_mfma_f32_16x16x32_bf16(af, bf0, acc0, 0, 0, 0);
        acc1 = __builtin_amdgcn_mfma_f32_16x16x32_bf16(af, bf1, acc1, 0, 0, 0);
    };

    ISSUE_F(Fb, "128", "144");              // kt1  (outstanding 12)
    WAITV(6); compute_kt(Fa, 0);
    ISSUE_F(Fa, "256", "272");              // kt2
    WAITV(6); compute_kt(Fb, 1);
    ISSUE_F(Fb, "384", "400");              // kt3
    WAITV(6); compute_kt(Fa, 2);
    ISSUE_F(Fa, "512", "528");              // kt4
    WAITV(6); compute_kt(Fb, 3);
    WAITV(0); compute_kt(Fa, 4);

    // ---- epilogue: all vmem after the gather ledger is drained ----
    if (lane < 16) out[p] = log1pf(expf(sig - 5.f));
#pragma unroll
    for (int nt = 0; nt < 2; ++nt) {
        int c = nt * 16 + lane16;
        f32x4 A = nt ? acc1 : acc0;
        if (c < PP) {
#pragma unroll
            for (int j = 0; j < 4; ++j) {
                int prow = wavebase + quad * 4 + j;
                X64[prow * 32 + c] = (unsigned short)__builtin_bit_cast(unsigned short, (__bf16)A[j]);
            }
        }
    }
    if (quad < 3) {
        float d = dird[p * 3 + quad];
        X64[p * 32 + 27 + quad] = (unsigned short)__builtin_bit_cast(unsigned short, (__bf16)d);
    } else {
        *(unsigned int*)(X64 + p * 32 + 30) = 0u;
    }
}

// ================= PHASE B: encode + 3-layer MLP, 32 points/wave =================
// 2 M-tiles per weight fetch (halves weight line-traffic). Wave-private tile, no barriers.
__global__ __launch_bounds__(256, 4)
void phaseB(const unsigned short* __restrict__ X64, const short* __restrict__ fr,
            const float* __restrict__ b1, const float* __restrict__ b2,
            const float* __restrict__ b3, float* __restrict__ out, int Np) {
    __shared__ char T[4 * 32 * 256];
    const int tid = threadIdx.x;
    const int wid = tid >> 6;
    const int lane = tid & 63;
    const int quad = lane >> 4, lane16 = lane & 15;
    const int rowbase = blockIdx.x * 128 + wid * 32;
    char* Tw = T + wid * 32 * 256;

    const short* W1F = fr + FR_W1;
    const short* W2F = fr + FR_W2;
    const short* W3F = fr + FR_W3;

    // ---- encode in-register -> layer-1 A-frags for both M-tiles ----
    short8 af[2][4];
#pragma unroll
    for (int mt = 0; mt < 2; ++mt)
#pragma unroll
        for (int kt = 0; kt < 4; ++kt) {
            unsigned int d = *(const unsigned int*)(X64 + (rowbase + mt * 16 + lane16) * 32 + kt * 8 + quad * 2);
            float f0 = bflo(d), f1 = bfhi(d);
            float s1 = __sinf(f0), c1 = __cosf(f0);
            float s2 = 2.f * s1 * c1, c2 = fmaf(-2.f * s1, s1, 1.f);
            float s1b = __sinf(f1), c1b = __cosf(f1);
            float s2b = 2.f * s1b * c1b, c2b = fmaf(-2.f * s1b, s1b, 1.f);
            u32x4 uu = {pk2bf(s1, c1), pk2bf(s2, c2), pk2bf(s1b, c1b), pk2bf(s2b, c2b)};
            af[mt][kt] = __builtin_bit_cast(short8, uu);
        }

    // ---- layers 1 & 2 ----
#pragma unroll 1
    for (int layer = 0; layer < 2; ++layer) {
        const short* WF = layer ? W2F : W1F;
        const float* bb = layer ? b2 : b1;
#pragma unroll 2
        for (int nt = 0; nt < 8; ++nt) {
            short8 wfv[4];
#pragma unroll
            for (int kt = 0; kt < 4; ++kt)
                wfv[kt] = *(const short8*)(WF + ((kt * 8 + nt) * 64 + lane) * 8);
            f32x4 acc[2];
#pragma unroll
            for (int mt = 0; mt < 2; ++mt) acc[mt] = {0.f, 0.f, 0.f, 0.f};
#pragma unroll
            for (int mt = 0; mt < 2; ++mt)
#pragma unroll
                for (int kt = 0; kt < 4; ++kt)
                    acc[mt] = __builtin_amdgcn_mfma_f32_16x16x32_bf16(af[mt][kt], wfv[kt], acc[mt], 0, 0, 0);

            float bvv = bb[nt * 16 + lane16];
#pragma unroll
            for (int mt = 0; mt < 2; ++mt)
#pragma unroll
                for (int j = 0; j < 4; ++j) {
                    float v = acc[mt][j] + bvv;
                    v = fmaxf(v, 0.01f * v);            // leaky relu
                    int row = mt * 16 + quad * 4 + j;
                    int byte = (nt * 16 + lane16) * 2;
                    int chunk = byte >> 4, off = byte & 15;
                    *(short*)(Tw + row * 256 + ((chunk ^ (row & 7)) << 4) + off) =
                        (short)__builtin_bit_cast(unsigned short, (__bf16)v);
                }
        }
        // wave-private tile: in-wave lgkmcnt ordering suffices
#pragma unroll
        for (int mt = 0; mt < 2; ++mt)
#pragma unroll
            for (int kt = 0; kt < 4; ++kt) {
                int row = mt * 16 + lane16;
                int chunk = kt * 4 + quad;
                af[mt][kt] = *(const short8*)(Tw + row * 256 + ((chunk ^ (row & 7)) << 4));
            }
    }

    // ---- layer 3: 128 -> 3 (+sigmoid) ----
    {
        short8 wf3[4];
#pragma unroll
        for (int kt = 0; kt < 4; ++kt)
            wf3[kt] = *(const short8*)(W3F + (kt * 64 + lane) * 8);
        f32x4 acc3[2];
#pragma unroll
        for (int mt = 0; mt < 2; ++mt) acc3[mt] = {0.f, 0.f, 0.f, 0.f};
#pragma unroll
        for (int mt = 0; mt < 2; ++mt)
#pragma unroll
            for (int kt = 0; kt < 4; ++kt)
                acc3[mt] = __builtin_amdgcn_mfma_f32_16x16x32_bf16(af[mt][kt], wf3[kt], acc3[mt], 0, 0, 0);

        if (lane16 < 3) {
            float bvv = b3[lane16];
#pragma unroll
            for (int mt = 0; mt < 2; ++mt)
#pragma unroll
                for (int j = 0; j < 4; ++j) {
                    float v = acc3[mt][j] + bvv;
                    float r = 1.f / (1.f + expf(-v));
                    int row = mt * 16 + quad * 4 + j;
                    out[Np + (rowbase + row) * 3 + lane16] = r;
                }
        }
    }
}

// ================= fused fallback (R5 kernel) if ws too small =================
__global__ __launch_bounds__(128, 4)
void tensorf_fused(const float* __restrict__ xyz, const float* __restrict__ dird,
                   const float* __restrict__ voxel,
                   const float* __restrict__ b1, const float* __restrict__ b2,
                   const float* __restrict__ b3,
                   const unsigned int* __restrict__ wt, const short* __restrict__ fr,
                   float* __restrict__ out, int Np) {
    __shared__ float voxs[3 * NV];
    __shared__ char  X[2 * 32 * 256];

    const int tid = threadIdx.x;
    const int wid = tid >> 6;
    const int lane = tid & 63;
    const int quad = lane >> 4, lane16 = lane & 15;
    const int wavebase = blockIdx.x * 64 + wid * 32;
    char* Xw = X + wid * 32 * 256;

    for (int i = tid; i < 3 * NV; i += 128) voxs[i] = voxel[i];
    __syncthreads();

    const unsigned int* SIGU  = wt;
    const unsigned int* FEATU = wt + SIG_D;
    const short* BFr = fr + FR_B;

#pragma unroll 1
    for (int q = 0; q < 2; ++q) {
        const int rowbase = q * 16;
        const int p = wavebase + rowbase + lane16;
        int ipb[3]; h2 wv[3];
#pragma unroll
        for (int a = 0; a < 3; ++a) {
            float x = xyz[p * 3 + a];
            int ind = (int)ceilf(x * 127.f);
            ind = min(max(ind, 0), 128);
            while (ind > 0 && voxs[a * NV + ind - 1] >= x) --ind;
            while (ind < 128 && voxs[a * NV + ind] < x) ++ind;
            int il = min(max(ind - 1, 0), 127);
            int ir = min(ind, 127);
            float vl = voxs[a * NV + il], vr = voxs[a * NV + ir];
            float w = (x - vl) / (vr - vl + 1e-6f);
            w = (il == 127) ? 1.f : w;
            ipb[a] = min(il, 126);
            wv[a] = h2{(_Float16)1.0f, (_Float16)w};
        }
        float sig = 0.f;
#pragma unroll
        for (int kt = 0; kt < 2; ++kt) {
            float pr[8];
#pragma unroll
            for (int a = 0; a < 3; ++a)
                lerpf8(SIGU + (a * NV + ipb[a]) * 64 + kt * 32 + quad * 8, wv[a], pr, a == 0);
#pragma unroll
            for (int j = 0; j < 8; ++j) sig += pr[j];
        }
        sig += __shfl_xor(sig, 16);
        sig += __shfl_xor(sig, 32);
        if (lane < 16) out[p] = log1pf(expf(sig - 5.f));

        f32x4 acc0 = {0.f, 0.f, 0.f, 0.f}, acc1 = {0.f, 0.f, 0.f, 0.f};
#pragma unroll
        for (int kt = 0; kt < 5; ++kt) {
            float pr[8];
#pragma unroll
            for (int a = 0; a < 3; ++a)
                lerpf8(FEATU + (a * NV + ipb[a]) * 160 + kt * 32 + quad * 8, wv[a], pr, a == 0);
            u32x4 uu;
#pragma unroll
            for (int d = 0; d < 4; ++d) uu[d] = pk2bf(pr[2 * d], pr[2 * d + 1]);
            short8 af = __builtin_bit_cast(short8, uu);
            short8 bf0 = *(const short8*)(BFr + ((kt * 2 + 0) * 64 + lane) * 8);
            short8 bf1 = *(const short8*)(BFr + ((kt * 2 + 1) * 64 + lane) * 8);
            acc0 = __builtin_amdgcn_mfma_f32_16x16x32_bf16(af, bf0, acc0, 0, 0, 0);
            acc1 = __builtin_amdgcn_mfma_f32_16x16x32_bf16(af, bf1, acc1, 0, 0, 0);
        }
#pragma unroll
        for (int nt = 0; nt < 2; ++nt) {
            int c = nt * 16 + lane16;
            f32x4 A = nt ? acc1 : acc0;
            if (c < PP) {
#pragma unroll
                for (int j = 0; j < 4; ++j) {
                    int row = rowbase + quad * 4 + j;
                    float f = A[j];
                    float s1 = __sinf(f), c1 = __cosf(f);
                    float s2 = 2.f * s1 * c1;
                    float c2 = fmaf(-2.f * s1, s1, 1.f);
                    unsigned int w0 = pk2bf(s1, c1);
                    unsigned int w1 = pk2bf(s2, c2);
                    int byte = c * 8;
                    int chunk = byte >> 4, off = byte & 15;
                    *(u32x2*)(Xw + row * 256 + ((chunk ^ (row & 7)) << 4) + off) = u32x2{w0, w1};
                }
            }
        }
        {
            int row = rowbase + lane16;
            if (quad < 3) {
                float d = dird[p * 3 + quad];
                float s1 = __sinf(d), c1 = __cosf(d);
                float s2 = 2.f * s1 * c1;
                float c2 = fmaf(-2.f * s1, s1, 1.f);
                unsigned int w0 = pk2bf(s1, c1);
                unsigned int w1 = pk2bf(s2, c2);
                int byte = 216 + 8 * quad;
                int chunk = byte >> 4, off = byte & 15;
                *(u32x2*)(Xw + row * 256 + ((chunk ^ (row & 7)) << 4) + off) = u32x2{w0, w1};
            } else {
                int addr = row * 256 + ((15 ^ (row & 7)) << 4);
                *(u32x4*)(Xw + addr) = u32x4{0u, 0u, 0u, 0u};
            }
        }
    }
    __syncthreads();

    const short* W1F = fr + FR_W1;
    const short* W2F = fr + FR_W2;
    const short* W3F = fr + FR_W3;

#pragma unroll 1
    for (int layer = 0; layer < 2; ++layer) {
        const short* WF = layer ? W2F : W1F;
        const float* bb = layer ? b2 : b1;
        short8 af[2][4];
#pragma unroll
        for (int m = 0; m < 2; ++m)
#pragma unroll
            for (int kt = 0; kt < 4; ++kt) {
                int row = m * 16 + lane16;
                int chunk = kt * 4 + quad;
                af[m][kt] = *(const short8*)(Xw + row * 256 + ((chunk ^ (row & 7)) << 4));
            }
#pragma unroll 1
        for (int nt = 0; nt < 8; ++nt) {
            short8 wfv[4];
#pragma unroll
            for (int kt = 0; kt < 4; ++kt)
                wfv[kt] = *(const short8*)(WF + ((kt * 8 + nt) * 64 + lane) * 8);
            f32x4 acc[2];
#pragma unroll
            for (int m = 0; m < 2; ++m) acc[m] = {0.f, 0.f, 0.f, 0.f};
#pragma unroll
            for (int m = 0; m < 2; ++m)
#pragma unroll
                for (int kt = 0; kt < 4; ++kt)
                    acc[m] = __builtin_amdgcn_mfma_f32_16x16x32_bf16(af[m][kt], wfv[kt], acc[m], 0, 0, 0);
            float bvv = bb[nt * 16 + lane16];
#pragma unroll
            for (int m = 0; m < 2; ++m) {
#pragma unroll
                for (int j = 0; j < 4; ++j) {
                    float v = acc[m][j] + bvv;
                    v = fmaxf(v, 0.01f * v);
                    int row = m * 16 + quad * 4 + j;
                    int byte = (nt * 16 + lane16) * 2;
                    int chunk = byte >> 4, off = byte & 15;
                    *(short*)(Xw + row * 256 + ((chunk ^ (row & 7)) << 4) + off) =
                        (short)__builtin_bit_cast(unsigned short, (__bf16)v);
                }
            }
        }
        __syncthreads();
    }
    {
        short8 af[2][4];
#pragma unroll
        for (int m = 0; m < 2; ++m)
#pragma unroll
            for (int kt = 0; kt < 4; ++kt) {
                int row = m * 16 + lane16;
                int chunk = kt * 4 + quad;
                af[m][kt] = *(const short8*)(Xw + row * 256 + ((chunk ^ (row & 7)) << 4));
            }
        short8 wf3[4];
#pragma unroll
        for (int kt = 0; kt < 4; ++kt)
            wf3[kt] = *(const short8*)(W3F + (kt * 64 + lane) * 8);
        f32x4 acc3[2];
#pragma unroll
        for (int m = 0; m < 2; ++m) acc3[m] = {0.f, 0.f, 0.f, 0.f};
#pragma unroll
        for (int m = 0; m < 2; ++m)
#pragma unroll
            for (int kt = 0; kt < 4; ++kt)
                acc3[m] = __builtin_amdgcn_mfma_f32_16x16x32_bf16(af[m][kt], wf3[kt], acc3[m], 0, 0, 0);
        if (lane16 < 3) {
            float bvv = b3[lane16];
#pragma unroll
            for (int m = 0; m < 2; ++m) {
#pragma unroll
                for (int j = 0; j < 4; ++j) {
                    float v = acc3[m][j] + bvv;
                    float r = 1.f / (1.f + expf(-v));
                    int row = m * 16 + quad * 4 + j;
                    out[Np + (wavebase + row) * 3 + lane16] = r;
                }
            }
        }
    }
}

// ---------------- launch ----------------
extern "C" void kernel_launch(void* const* d_in, const int* in_sizes, int n_in,
                              void* d_out, int out_size, void* d_ws, size_t ws_size,
                              hipStream_t stream) {
    (void)n_in; (void)out_size;
    const float* xyz      = (const float*)d_in[0];
    const float* dird     = (const float*)d_in[1];
    const float* voxel    = (const float*)d_in[2];
    const float* sigma    = (const float*)d_in[3];
    const float* feature  = (const float*)d_in[4];
    const float* Bm       = (const float*)d_in[5];
    const float* W1       = (const float*)d_in[6];
    const float* b1       = (const float*)d_in[7];
    const float* W2       = (const float*)d_in[8];
    const float* b2       = (const float*)d_in[9];
    const float* W3       = (const float*)d_in[10];
    const float* b3       = (const float*)d_in[11];
    float* out = (float*)d_out;
    unsigned int* wt = (unsigned int*)d_ws;
    short* frg = (short*)d_ws + 2 * (size_t)NPAIR;

    const int Np = in_sizes[0] / 3;   // 524288
    const size_t base = (size_t)NPAIR * 4 + (size_t)FR_TOT * 2;
    const size_t need = base + (size_t)Np * 64;

    prep_tables<<<(NPAIR + 255) / 256, 256, 0, stream>>>(sigma, feature, wt);
    prep_frags<<<(FR_TOT + 255) / 256, 256, 0, stream>>>(Bm, W1, W2, W3, frg);

    if (ws_size >= need) {
        unsigned short* X64 = (unsigned short*)((char*)d_ws + base);
        phaseA<<<Np / 64, 256, 0, stream>>>(xyz, dird, voxel, wt, frg, out, X64, Np);
        phaseB<<<Np / 128, 256, 0, stream>>>(X64, frg, b1, b2, b3, out, Np);
    } else {
        tensorf_fused<<<Np / 64, 128, 0, stream>>>(xyz, dird, voxel, b1, b2, b3, wt, frg, out, Np);
    }
}

// Round 9
// 222.878 us; speedup vs baseline: 1.2163x; 1.0675x over previous
//
#include <hip/hip_runtime.h>
#include <cstdint>

// ---------------- problem constants ----------------
constexpr int RS  = 48;
constexpr int RC  = 144;
constexpr int PP  = 27;
constexpr int NV  = 128;
constexpr int CHN = 128;

// ---------------- ws layout ----------------
constexpr int SIG_D  = 3 * NV * 64;    // 24576 dwords
constexpr int FEAT_D = 3 * NV * 160;   // 61440 dwords
constexpr int NPAIR  = SIG_D + FEAT_D; // 86016 dwords = 344KB
constexpr int FR_B  = 0;               // B frags OLD map [5][2][64][8] = 5120 (fallback)
constexpr int FR_W1 = 5120;            // W1 frags [4][8][64][8] = 16384
constexpr int FR_W2 = 21504;
constexpr int FR_W3 = 37888;           // [4][64][8] = 2048
constexpr int FR_B2 = 39936;           // B frags NEW line-per-instruction map = 5120
constexpr int FR_TOT = 45056;

typedef __attribute__((ext_vector_type(8))) short short8;
typedef __attribute__((ext_vector_type(4))) float f32x4;
typedef __attribute__((ext_vector_type(2))) unsigned int u32x2;
typedef __attribute__((ext_vector_type(4))) unsigned int u32x4;
typedef _Float16 h2 __attribute__((ext_vector_type(2)));

__device__ __forceinline__ short f2bf(float f) {
    unsigned int u = __builtin_bit_cast(unsigned int, f);
    u += 0x7fffu + ((u >> 16) & 1u);
    return (short)(u >> 16);
}
__device__ __forceinline__ unsigned int pk2bf(float a, float b) {
    unsigned short ua = __builtin_bit_cast(unsigned short, (__bf16)a);
    unsigned short ub = __builtin_bit_cast(unsigned short, (__bf16)b);
    return (unsigned int)ua | ((unsigned int)ub << 16);
}
__device__ __forceinline__ float bflo(unsigned int u) { return __builtin_bit_cast(float, u << 16); }
__device__ __forceinline__ float bfhi(unsigned int u) { return __builtin_bit_cast(float, u & 0xffff0000u); }
__device__ __forceinline__ float dot2lerp(unsigned int lodelta, h2 wv) {
#if __has_builtin(__builtin_amdgcn_fdot2)
    return __builtin_amdgcn_fdot2(__builtin_bit_cast(h2, lodelta), wv, 0.f, false);
#else
    h2 a = __builtin_bit_cast(h2, lodelta);
    return (float)a.x * (float)wv.x + (float)a.y * (float)wv.y;
#endif
}

// inline-asm gather with literal offset; early-clobber dest; volatile preserves issue order
#define GLO(dst, base, OFF) \
    asm volatile("global_load_dwordx4 %0, %1, off offset:" OFF : "=&v"(dst) : "v"(base))
#define WAITV(N) do { asm volatile("s_waitcnt vmcnt(" #N ")" ::: "memory"); \
                      __builtin_amdgcn_sched_barrier(0); } while (0)
// one kt = 2 lines x 3 axes, each load covers ONE 64B line per point
#define ISSUE_FK(buf, O1, O2) do { \
    GLO(buf[0], fb0, O1); GLO(buf[1], fb0, O2); \
    GLO(buf[2], fb1, O1); GLO(buf[3], fb1, O2); \
    GLO(buf[4], fb2, O1); GLO(buf[5], fb2, O2); } while (0)

// ---------------- prep 1: f16 (lo, delta) packed tables ----------------
__global__ void prep_tables(const float* __restrict__ sigma, const float* __restrict__ feature,
                            unsigned int* __restrict__ wt) {
    int idx = blockIdx.x * 256 + threadIdx.x;
    if (idx >= NPAIR) return;
    float lo = 0.f, hi = 0.f;
    if (idx < SIG_D) {
        int a = idx / 8192, t = idx % 8192;
        int v = t / 64, r = t % 64;
        if (r < RS) {
            lo = sigma[(a * RS + r) * NV + v];
            hi = sigma[(a * RS + r) * NV + min(v + 1, NV - 1)];
        }
    } else {
        int j = idx - SIG_D;
        int a = j / 20480, t = j % 20480;
        int v = t / 160, r = t % 160;
        if (r < RC) {
            lo = feature[(a * RC + r) * NV + v];
            hi = feature[(a * RC + r) * NV + min(v + 1, NV - 1)];
        }
    }
    _Float16 lh = (_Float16)lo;
    _Float16 dh = (_Float16)(hi - lo);
    wt[idx] = (unsigned int)__builtin_bit_cast(unsigned short, lh) |
              ((unsigned int)__builtin_bit_cast(unsigned short, dh) << 16);
}

// ---------------- prep 2: bf16 fragment-layout weights ----------------
__global__ void prep_frags(const float* __restrict__ Bm, const float* __restrict__ W1,
                           const float* __restrict__ W2, const float* __restrict__ W3,
                           short* __restrict__ fr) {
    int idx = blockIdx.x * 256 + threadIdx.x;
    if (idx >= FR_TOT) return;
    float val = 0.f;
    if (idx < FR_W1) {                          // B frags (old map, fused fallback)
        int j = idx - FR_B;
        int frag = j >> 9, li = (j >> 3) & 63, e = j & 7;
        int kt = frag >> 1, nt = frag & 1;
        int k = kt * 32 + (li >> 4) * 8 + e;
        int n = nt * 16 + (li & 15);
        val = (k < RC && n < PP) ? Bm[k * PP + n] : 0.f;
    } else if (idx < FR_W2) {                   // W1 frags, permuted rows
        int j = idx - FR_W1;
        int frag = j >> 9, li = (j >> 3) & 63, e = j & 7;
        int kt = frag >> 3, nt = frag & 7;
        int kn = kt * 32 + (li >> 4) * 8 + e;
        int n = nt * 16 + (li & 15);
        if (kn < 120) {
            int ko;
            if (kn < 108) { ko = (kn & 3) * PP + (kn >> 2); }
            else { int t2 = kn - 108; ko = 108 + (t2 & 3) * 3 + (t2 >> 2); }
            val = W1[ko * CHN + n];
        }
    } else if (idx < FR_W3) {                   // W2 frags
        int j = idx - FR_W2;
        int frag = j >> 9, li = (j >> 3) & 63, e = j & 7;
        int kt = frag >> 3, nt = frag & 7;
        int k = kt * 32 + (li >> 4) * 8 + e;
        int n = nt * 16 + (li & 15);
        val = W2[k * CHN + n];
    } else if (idx < FR_B2) {                   // W3 frags
        int j = idx - FR_W3;
        int frag = j >> 9, li = (j >> 3) & 63, e = j & 7;
        int kt = frag;
        int k = kt * 32 + (li >> 4) * 8 + e;
        int n = li & 15;
        val = (n < 3) ? W3[k * 3 + n] : 0.f;
    } else {                                    // B frags, NEW line-per-instruction k-map
        int j = idx - FR_B2;
        int frag = j >> 9, li = (j >> 3) & 63, e = j & 7;
        int kt = frag >> 1, nt = frag & 1;
        int q = li >> 4;
        int n = nt * 16 + (li & 15);
        int k = -1;
        if (kt < 4) k = kt * 32 + (e < 4 ? 4 * q + e : 16 + 4 * q + (e - 4));
        else if (e < 4) k = 128 + 4 * q + e;     // kt4: half-width, e>=4 zero
        val = (k >= 0 && k < RC && n < PP) ? Bm[k * PP + n] : 0.f;
    }
    fr[idx] = f2bf(val);
}

__device__ __forceinline__ void lerpregs(u32x4 A, u32x4 Bv, h2 wv, float* pr, bool first) {
#pragma unroll
    for (int d = 0; d < 4; ++d) {
        float s0 = dot2lerp(A[d], wv);
        float s1 = dot2lerp(Bv[d], wv);
        if (first) { pr[d] = s0; pr[4 + d] = s1; }
        else       { pr[d] *= s0; pr[4 + d] *= s1; }
    }
}
__device__ __forceinline__ void lerpf8(const unsigned int* rl, h2 wv, float* pr, bool first) {
    u32x4 A  = *(const u32x4*)rl;
    u32x4 Bv = *(const u32x4*)(rl + 4);
    lerpregs(A, Bv, wv, pr, first);
}

// ================= PHASE A: line-per-instruction gathers + asm vmcnt pipeline =========
// Every gather instruction touches exactly ONE 64B line per point: 36 line-requests/point
// (9 sigma + 27 feats), vs 84 in the quad-strided layout. Pad lines never loaded.
__global__ __launch_bounds__(256, 4)
void phaseA(const float* __restrict__ xyz, const float* __restrict__ dird,
            const float* __restrict__ voxel,
            const unsigned int* __restrict__ wt, const short* __restrict__ fr,
            float* __restrict__ out, unsigned short* __restrict__ X64, int Np) {
    __shared__ float voxs[3 * NV];
    __shared__ short bfrs[5120];           // B frags (new map), 10KB

    const int tid = threadIdx.x;
    const int wid = tid >> 6;
    const int lane = tid & 63;
    const int quad = lane >> 4, lane16 = lane & 15;
    const int wavebase = blockIdx.x * 64 + wid * 16;
    const int p = wavebase + lane16;

    for (int i = tid; i < 3 * NV; i += 256) voxs[i] = voxel[i];
    for (int i = tid; i < 640; i += 256)
        ((short8*)bfrs)[i] = ((const short8*)(fr + FR_B2))[i];
    __syncthreads();

    const unsigned int* SIGU  = wt;
    const unsigned int* FEATU = wt + SIG_D;

    int ipb[3]; h2 wv[3];
#pragma unroll
    for (int a = 0; a < 3; ++a) {
        float x = xyz[p * 3 + a];
        int ind = (int)ceilf(x * 127.f);
        ind = min(max(ind, 0), 128);
        while (ind > 0 && voxs[a * NV + ind - 1] >= x) --ind;
        while (ind < 128 && voxs[a * NV + ind] < x) ++ind;
        int il = min(max(ind - 1, 0), 127);
        int ir = min(ind, 127);
        float vl = voxs[a * NV + il], vr = voxs[a * NV + ir];
        float w = (x - vl) / (vr - vl + 1e-6f);
        w = (il == 127) ? 1.f : w;
        ipb[a] = min(il, 126);
        wv[a] = h2{(_Float16)1.0f, (_Float16)w};
    }

    // per-axis bases include quad*16B: load L hits line L only
    const unsigned int* sb0 = SIGU + (0 * NV + ipb[0]) * 64 + quad * 4;
    const unsigned int* sb1 = SIGU + (1 * NV + ipb[1]) * 64 + quad * 4;
    const unsigned int* sb2 = SIGU + (2 * NV + ipb[2]) * 64 + quad * 4;
    const unsigned int* fb0 = FEATU + (0 * NV + ipb[0]) * 160 + quad * 4;
    const unsigned int* fb1 = FEATU + (1 * NV + ipb[1]) * 160 + quad * 4;
    const unsigned int* fb2 = FEATU + (2 * NV + ipb[2]) * 160 + quad * 4;

    // ---- issue sigma (9 lines: ranks 0..47) + feats kt0 (6) ----
    u32x4 S[9];
    GLO(S[0], sb0, "0");   GLO(S[1], sb1, "0");   GLO(S[2], sb2, "0");
    GLO(S[3], sb0, "64");  GLO(S[4], sb1, "64");  GLO(S[5], sb2, "64");
    GLO(S[6], sb0, "128"); GLO(S[7], sb1, "128"); GLO(S[8], sb2, "128");
    u32x4 Fa[6], Fb[6];
    ISSUE_FK(Fa, "0", "64");                  // kt0 -> 15 outstanding

    WAITV(6);                                  // sigma arrived (kt0 still flying)
    float sig = 0.f;
#pragma unroll
    for (int L = 0; L < 3; ++L)
#pragma unroll
        for (int j = 0; j < 4; ++j)
            sig += dot2lerp(S[3 * L][j], wv[0]) * dot2lerp(S[3 * L + 1][j], wv[1])
                 * dot2lerp(S[3 * L + 2][j], wv[2]);
    sig += __shfl_xor(sig, 16);
    sig += __shfl_xor(sig, 32);

    f32x4 acc0 = {0.f, 0.f, 0.f, 0.f}, acc1 = {0.f, 0.f, 0.f, 0.f};
    auto compute_kt = [&](const u32x4* F, int kt) {
        float pr[8];
#pragma unroll
        for (int j = 0; j < 4; ++j) {
            pr[j]     = dot2lerp(F[0][j], wv[0]) * dot2lerp(F[2][j], wv[1]) * dot2lerp(F[4][j], wv[2]);
            pr[4 + j] = dot2lerp(F[1][j], wv[0]) * dot2lerp(F[3][j], wv[1]) * dot2lerp(F[5][j], wv[2]);
        }
        u32x4 uu;
#pragma unroll
        for (int d = 0; d < 4; ++d) uu[d] = pk2bf(pr[2 * d], pr[2 * d + 1]);
        short8 af = __builtin_bit_cast(short8, uu);
        short8 bf0 = *(const short8*)(bfrs + ((kt * 2 + 0) * 64 + lane) * 8);
        short8 bf1 = *(const short8*)(bfrs + ((kt * 2 + 1) * 64 + lane) * 8);
        acc0 = __builtin_amdgcn_mfma_f32_16x16x32_bf16(af, bf0, acc0, 0, 0, 0);
        acc1 = __builtin_amdgcn_mfma_f32_16x16x32_bf16(af, bf1, acc1, 0, 0, 0);
    };

    ISSUE_FK(Fb, "128", "192");               // kt1 (12 out)
    WAITV(6); compute_kt(Fa, 0);
    ISSUE_FK(Fa, "256", "320");               // kt2 (12 out)
    WAITV(6); compute_kt(Fb, 1);
    ISSUE_FK(Fb, "384", "448");               // kt3 (12 out)
    WAITV(6); compute_kt(Fa, 2);
    GLO(Fa[0], fb0, "512"); GLO(Fa[1], fb1, "512"); GLO(Fa[2], fb2, "512");  // kt4 (9 out)
    WAITV(3); compute_kt(Fb, 3);
    WAITV(0);
    {   // kt4: 16 ranks (line 8), upper half zero
        float pr[8];
#pragma unroll
        for (int j = 0; j < 4; ++j) {
            pr[j] = dot2lerp(Fa[0][j], wv[0]) * dot2lerp(Fa[1][j], wv[1]) * dot2lerp(Fa[2][j], wv[2]);
            pr[4 + j] = 0.f;
        }
        u32x4 uu;
#pragma unroll
        for (int d = 0; d < 4; ++d) uu[d] = pk2bf(pr[2 * d], pr[2 * d + 1]);
        short8 af = __builtin_bit_cast(short8, uu);
        short8 bf0 = *(const short8*)(bfrs + ((4 * 2 + 0) * 64 + lane) * 8);
        short8 bf1 = *(const short8*)(bfrs + ((4 * 2 + 1) * 64 + lane) * 8);
        acc0 = __builtin_amdgcn_mfma_f32_16x16x32_bf16(af, bf0, acc0, 0, 0, 0);
        acc1 = __builtin_amdgcn_mfma_f32_16x16x32_bf16(af, bf1, acc1, 0, 0, 0);
    }

    // ---- epilogue: all stores after the gather ledger is drained ----
    if (lane < 16) out[p] = log1pf(expf(sig - 5.f));
#pragma unroll
    for (int nt = 0; nt < 2; ++nt) {
        int c = nt * 16 + lane16;
        f32x4 A = nt ? acc1 : acc0;
        if (c < PP) {
#pragma unroll
            for (int j = 0; j < 4; ++j) {
                int prow = wavebase + quad * 4 + j;
                X64[prow * 32 + c] = (unsigned short)__builtin_bit_cast(unsigned short, (__bf16)A[j]);
            }
        }
    }
    if (quad < 3) {
        float d = dird[p * 3 + quad];
        X64[p * 32 + 27 + quad] = (unsigned short)__builtin_bit_cast(unsigned short, (__bf16)d);
    } else {
        *(unsigned int*)(X64 + p * 32 + 30) = 0u;
    }
}

// ================= PHASE B: encode + 3-layer MLP, 32 points/wave =================
__global__ __launch_bounds__(256, 4)
void phaseB(const unsigned short* __restrict__ X64, const short* __restrict__ fr,
            const float* __restrict__ b1, const float* __restrict__ b2,
            const float* __restrict__ b3, float* __restrict__ out, int Np) {
    __shared__ char T[4 * 32 * 256];
    const int tid = threadIdx.x;
    const int wid = tid >> 6;
    const int lane = tid & 63;
    const int quad = lane >> 4, lane16 = lane & 15;
    const int rowbase = blockIdx.x * 128 + wid * 32;
    char* Tw = T + wid * 32 * 256;

    const short* W1F = fr + FR_W1;
    const short* W2F = fr + FR_W2;
    const short* W3F = fr + FR_W3;

    short8 af[2][4];
#pragma unroll
    for (int mt = 0; mt < 2; ++mt)
#pragma unroll
        for (int kt = 0; kt < 4; ++kt) {
            unsigned int d = *(const unsigned int*)(X64 + (rowbase + mt * 16 + lane16) * 32 + kt * 8 + quad * 2);
            float f0 = bflo(d), f1 = bfhi(d);
            float s1 = __sinf(f0), c1 = __cosf(f0);
            float s2 = 2.f * s1 * c1, c2 = fmaf(-2.f * s1, s1, 1.f);
            float s1b = __sinf(f1), c1b = __cosf(f1);
            float s2b = 2.f * s1b * c1b, c2b = fmaf(-2.f * s1b, s1b, 1.f);
            u32x4 uu = {pk2bf(s1, c1), pk2bf(s2, c2), pk2bf(s1b, c1b), pk2bf(s2b, c2b)};
            af[mt][kt] = __builtin_bit_cast(short8, uu);
        }

#pragma unroll 1
    for (int layer = 0; layer < 2; ++layer) {
        const short* WF = layer ? W2F : W1F;
        const float* bb = layer ? b2 : b1;
#pragma unroll 2
        for (int nt = 0; nt < 8; ++nt) {
            short8 wfv[4];
#pragma unroll
            for (int kt = 0; kt < 4; ++kt)
                wfv[kt] = *(const short8*)(WF + ((kt * 8 + nt) * 64 + lane) * 8);
            f32x4 acc[2];
#pragma unroll
            for (int mt = 0; mt < 2; ++mt) acc[mt] = {0.f, 0.f, 0.f, 0.f};
#pragma unroll
            for (int mt = 0; mt < 2; ++mt)
#pragma unroll
                for (int kt = 0; kt < 4; ++kt)
                    acc[mt] = __builtin_amdgcn_mfma_f32_16x16x32_bf16(af[mt][kt], wfv[kt], acc[mt], 0, 0, 0);

            float bvv = bb[nt * 16 + lane16];
#pragma unroll
            for (int mt = 0; mt < 2; ++mt)
#pragma unroll
                for (int j = 0; j < 4; ++j) {
                    float v = acc[mt][j] + bvv;
                    v = fmaxf(v, 0.01f * v);
                    int row = mt * 16 + quad * 4 + j;
                    int byte = (nt * 16 + lane16) * 2;
                    int chunk = byte >> 4, off = byte & 15;
                    *(short*)(Tw + row * 256 + ((chunk ^ (row & 7)) << 4) + off) =
                        (short)__builtin_bit_cast(unsigned short, (__bf16)v);
                }
        }
#pragma unroll
        for (int mt = 0; mt < 2; ++mt)
#pragma unroll
            for (int kt = 0; kt < 4; ++kt) {
                int row = mt * 16 + lane16;
                int chunk = kt * 4 + quad;
                af[mt][kt] = *(const short8*)(Tw + row * 256 + ((chunk ^ (row & 7)) << 4));
            }
    }

    {
        short8 wf3[4];
#pragma unroll
        for (int kt = 0; kt < 4; ++kt)
            wf3[kt] = *(const short8*)(W3F + (kt * 64 + lane) * 8);
        f32x4 acc3[2];
#pragma unroll
        for (int mt = 0; mt < 2; ++mt) acc3[mt] = {0.f, 0.f, 0.f, 0.f};
#pragma unroll
        for (int mt = 0; mt < 2; ++mt)
#pragma unroll
            for (int kt = 0; kt < 4; ++kt)
                acc3[mt] = __builtin_amdgcn_mfma_f32_16x16x32_bf16(af[mt][kt], wf3[kt], acc3[mt], 0, 0, 0);

        if (lane16 < 3) {
            float bvv = b3[lane16];
#pragma unroll
            for (int mt = 0; mt < 2; ++mt)
#pragma unroll
                for (int j = 0; j < 4; ++j) {
                    float v = acc3[mt][j] + bvv;
                    float r = 1.f / (1.f + expf(-v));
                    int row = mt * 16 + quad * 4 + j;
                    out[Np + (rowbase + row) * 3 + lane16] = r;
                }
        }
    }
}

// ================= fused fallback (uses OLD B-frag map) if ws too small =================
__global__ __launch_bounds__(128, 4)
void tensorf_fused(const float* __restrict__ xyz, const float* __restrict__ dird,
                   const float* __restrict__ voxel,
                   const float* __restrict__ b1, const float* __restrict__ b2,
                   const float* __restrict__ b3,
                   const unsigned int* __restrict__ wt, const short* __restrict__ fr,
                   float* __restrict__ out, int Np) {
    __shared__ float voxs[3 * NV];
    __shared__ char  X[2 * 32 * 256];

    const int tid = threadIdx.x;
    const int wid = tid >> 6;
    const int lane = tid & 63;
    const int quad = lane >> 4, lane16 = lane & 15;
    const int wavebase = blockIdx.x * 64 + wid * 32;
    char* Xw = X + wid * 32 * 256;

    for (int i = tid; i < 3 * NV; i += 128) voxs[i] = voxel[i];
    __syncthreads();

    const unsigned int* SIGU  = wt;
    const unsigned int* FEATU = wt + SIG_D;
    const short* BFr = fr + FR_B;

#pragma unroll 1
    for (int q = 0; q < 2; ++q) {
        const int rowbase = q * 16;
        const int p = wavebase + rowbase + lane16;
        int ipb[3]; h2 wv[3];
#pragma unroll
        for (int a = 0; a < 3; ++a) {
            float x = xyz[p * 3 + a];
            int ind = (int)ceilf(x * 127.f);
            ind = min(max(ind, 0), 128);
            while (ind > 0 && voxs[a * NV + ind - 1] >= x) --ind;
            while (ind < 128 && voxs[a * NV + ind] < x) ++ind;
            int il = min(max(ind - 1, 0), 127);
            int ir = min(ind, 127);
            float vl = voxs[a * NV + il], vr = voxs[a * NV + ir];
            float w = (x - vl) / (vr - vl + 1e-6f);
            w = (il == 127) ? 1.f : w;
            ipb[a] = min(il, 126);
            wv[a] = h2{(_Float16)1.0f, (_Float16)w};
        }
        float sig = 0.f;
#pragma unroll
        for (int kt = 0; kt < 2; ++kt) {
            float pr[8];
#pragma unroll
            for (int a = 0; a < 3; ++a)
                lerpf8(SIGU + (a * NV + ipb[a]) * 64 + kt * 32 + quad * 8, wv[a], pr, a == 0);
#pragma unroll
            for (int j = 0; j < 8; ++j) sig += pr[j];
        }
        sig += __shfl_xor(sig, 16);
        sig += __shfl_xor(sig, 32);
        if (lane < 16) out[p] = log1pf(expf(sig - 5.f));

        f32x4 acc0 = {0.f, 0.f, 0.f, 0.f}, acc1 = {0.f, 0.f, 0.f, 0.f};
#pragma unroll
        for (int kt = 0; kt < 5; ++kt) {
            float pr[8];
#pragma unroll
            for (int a = 0; a < 3; ++a)
                lerpf8(FEATU + (a * NV + ipb[a]) * 160 + kt * 32 + quad * 8, wv[a], pr, a == 0);
            u32x4 uu;
#pragma unroll
            for (int d = 0; d < 4; ++d) uu[d] = pk2bf(pr[2 * d], pr[2 * d + 1]);
            short8 af = __builtin_bit_cast(short8, uu);
            short8 bf0 = *(const short8*)(BFr + ((kt * 2 + 0) * 64 + lane) * 8);
            short8 bf1 = *(const short8*)(BFr + ((kt * 2 + 1) * 64 + lane) * 8);
            acc0 = __builtin_amdgcn_mfma_f32_16x16x32_bf16(af, bf0, acc0, 0, 0, 0);
            acc1 = __builtin_amdgcn_mfma_f32_16x16x32_bf16(af, bf1, acc1, 0, 0, 0);
        }
#pragma unroll
        for (int nt = 0; nt < 2; ++nt) {
            int c = nt * 16 + lane16;
            f32x4 A = nt ? acc1 : acc0;
            if (c < PP) {
#pragma unroll
                for (int j = 0; j < 4; ++j) {
                    int row = rowbase + quad * 4 + j;
                    float f = A[j];
                    float s1 = __sinf(f), c1 = __cosf(f);
                    float s2 = 2.f * s1 * c1;
                    float c2 = fmaf(-2.f * s1, s1, 1.f);
                    unsigned int w0 = pk2bf(s1, c1);
                    unsigned int w1 = pk2bf(s2, c2);
                    int byte = c * 8;
                    int chunk = byte >> 4, off = byte & 15;
                    *(u32x2*)(Xw + row * 256 + ((chunk ^ (row & 7)) << 4) + off) = u32x2{w0, w1};
                }
            }
        }
        {
            int row = rowbase + lane16;
            if (quad < 3) {
                float d = dird[p * 3 + quad];
                float s1 = __sinf(d), c1 = __cosf(d);
                float s2 = 2.f * s1 * c1;
                float c2 = fmaf(-2.f * s1, s1, 1.f);
                unsigned int w0 = pk2bf(s1, c1);
                unsigned int w1 = pk2bf(s2, c2);
                int byte = 216 + 8 * quad;
                int chunk = byte >> 4, off = byte & 15;
                *(u32x2*)(Xw + row * 256 + ((chunk ^ (row & 7)) << 4) + off) = u32x2{w0, w1};
            } else {
                int addr = row * 256 + ((15 ^ (row & 7)) << 4);
                *(u32x4*)(Xw + addr) = u32x4{0u, 0u, 0u, 0u};
            }
        }
    }
    __syncthreads();

    const short* W1F = fr + FR_W1;
    const short* W2F = fr + FR_W2;
    const short* W3F = fr + FR_W3;

#pragma unroll 1
    for (int layer = 0; layer < 2; ++layer) {
        const short* WF = layer ? W2F : W1F;
        const float* bb = layer ? b2 : b1;
        short8 af[2][4];
#pragma unroll
        for (int m = 0; m < 2; ++m)
#pragma unroll
            for (int kt = 0; kt < 4; ++kt) {
                int row = m * 16 + lane16;
                int chunk = kt * 4 + quad;
                af[m][kt] = *(const short8*)(Xw + row * 256 + ((chunk ^ (row & 7)) << 4));
            }
#pragma unroll 1
        for (int nt = 0; nt < 8; ++nt) {
            short8 wfv[4];
#pragma unroll
            for (int kt = 0; kt < 4; ++kt)
                wfv[kt] = *(const short8*)(WF + ((kt * 8 + nt) * 64 + lane) * 8);
            f32x4 acc[2];
#pragma unroll
            for (int m = 0; m < 2; ++m) acc[m] = {0.f, 0.f, 0.f, 0.f};
#pragma unroll
            for (int m = 0; m < 2; ++m)
#pragma unroll
                for (int kt = 0; kt < 4; ++kt)
                    acc[m] = __builtin_amdgcn_mfma_f32_16x16x32_bf16(af[m][kt], wfv[kt], acc[m], 0, 0, 0);
            float bvv = bb[nt * 16 + lane16];
#pragma unroll
            for (int m = 0; m < 2; ++m) {
#pragma unroll
                for (int j = 0; j < 4; ++j) {
                    float v = acc[m][j] + bvv;
                    v = fmaxf(v, 0.01f * v);
                    int row = m * 16 + quad * 4 + j;
                    int byte = (nt * 16 + lane16) * 2;
                    int chunk = byte >> 4, off = byte & 15;
                    *(short*)(Xw + row * 256 + ((chunk ^ (row & 7)) << 4) + off) =
                        (short)__builtin_bit_cast(unsigned short, (__bf16)v);
                }
            }
        }
        __syncthreads();
    }
    {
        short8 af[2][4];
#pragma unroll
        for (int m = 0; m < 2; ++m)
#pragma unroll
            for (int kt = 0; kt < 4; ++kt) {
                int row = m * 16 + lane16;
                int chunk = kt * 4 + quad;
                af[m][kt] = *(const short8*)(Xw + row * 256 + ((chunk ^ (row & 7)) << 4));
            }
        short8 wf3[4];
#pragma unroll
        for (int kt = 0; kt < 4; ++kt)
            wf3[kt] = *(const short8*)(W3F + (kt * 64 + lane) * 8);
        f32x4 acc3[2];
#pragma unroll
        for (int m = 0; m < 2; ++m) acc3[m] = {0.f, 0.f, 0.f, 0.f};
#pragma unroll
        for (int m = 0; m < 2; ++m)
#pragma unroll
            for (int kt = 0; kt < 4; ++kt)
                acc3[m] = __builtin_amdgcn_mfma_f32_16x16x32_bf16(af[m][kt], wf3[kt], acc3[m], 0, 0, 0);
        if (lane16 < 3) {
            float bvv = b3[lane16];
#pragma unroll
            for (int m = 0; m < 2; ++m) {
#pragma unroll
                for (int j = 0; j < 4; ++j) {
                    float v = acc3[m][j] + bvv;
                    float r = 1.f / (1.f + expf(-v));
                    int row = m * 16 + quad * 4 + j;
                    out[Np + (wavebase + row) * 3 + lane16] = r;
                }
            }
        }
    }
}

// ---------------- launch ----------------
extern "C" void kernel_launch(void* const* d_in, const int* in_sizes, int n_in,
                              void* d_out, int out_size, void* d_ws, size_t ws_size,
                              hipStream_t stream) {
    (void)n_in; (void)out_size;
    const float* xyz      = (const float*)d_in[0];
    const float* dird     = (const float*)d_in[1];
    const float* voxel    = (const float*)d_in[2];
    const float* sigma    = (const float*)d_in[3];
    const float* feature  = (const float*)d_in[4];
    const float* Bm       = (const float*)d_in[5];
    const float* W1       = (const float*)d_in[6];
    const float* b1       = (const float*)d_in[7];
    const float* W2       = (const float*)d_in[8];
    const float* b2       = (const float*)d_in[9];
    const float* W3       = (const float*)d_in[10];
    const float* b3       = (const float*)d_in[11];
    float* out = (float*)d_out;
    unsigned int* wt = (unsigned int*)d_ws;
    short* frg = (short*)d_ws + 2 * (size_t)NPAIR;

    const int Np = in_sizes[0] / 3;   // 524288
    const size_t base = (size_t)NPAIR * 4 + (size_t)FR_TOT * 2;
    const size_t need = base + (size_t)Np * 64;

    prep_tables<<<(NPAIR + 255) / 256, 256, 0, stream>>>(sigma, feature, wt);
    prep_frags<<<(FR_TOT + 255) / 256, 256, 0, stream>>>(Bm, W1, W2, W3, frg);

    if (ws_size >= need) {
        unsigned short* X64 = (unsigned short*)((char*)d_ws + base);
        phaseA<<<Np / 64, 256, 0, stream>>>(xyz, dird, voxel, wt, frg, out, X64, Np);
        phaseB<<<Np / 128, 256, 0, stream>>>(X64, frg, b1, b2, b3, out, Np);
    } else {
        tensorf_fused<<<Np / 64, 128, 0, stream>>>(xyz, dird, voxel, b1, b2, b3, wt, frg, out, Np);
    }
}